// Round 13
// baseline (3708.090 us; speedup 1.0000x reference)
//
#include <hip/hip_runtime.h>

typedef unsigned short u16;
typedef unsigned int u32;
typedef __attribute__((ext_vector_type(8))) short bf16x8;   // 8 bf16 = 4 VGPRs (MFMA A/B frag)
typedef __attribute__((ext_vector_type(4))) float f32x4;    // MFMA C/D frag

// ---------- constants ----------
#define TSEQ 32      // LSTM time steps (reshape bug: seq runs over B)
#define NB   128     // LSTM batch
#define HDIM 400
#define KPAD 416     // 400 padded to 13*32 for MFMA K
#define G4   1600    // 4*H
#define TOK  4096    // 32*128 tokens
#define XGC  3200    // both dirs' gate cols
#define BPITCH 420   // LDS h pitch (shorts): 840B -> 16 distinct banks across fr lanes

__device__ __forceinline__ float b2f(u16 u) {
  union { unsigned int i; float f; } v; v.i = ((unsigned int)u) << 16; return v.f;
}
__device__ __forceinline__ u16 f2b(float f) {
  union { float fl; unsigned int i; } v; v.fl = f;
  unsigned int r = v.i + 0x7fffu + ((v.i >> 16) & 1u);   // RNE
  return (u16)(r >> 16);
}
__device__ __forceinline__ float sigm_(float x) { return 1.0f / (1.0f + __expf(-x)); }
__device__ __forceinline__ float tanh_(float x) {
  float e = __expf(2.0f * x);
  return 1.0f - 2.0f / (e + 1.0f);   // exact limits at +-inf, no NaN
}

// ---------- fused weight prep + embedding (inputs fp32, verified r3..r12) ----------
// arranged gate row: ar = ctile*64 + type*16 + j  <->  orig row = type*400 + ctile*16 + j
__global__ __launch_bounds__(256) void prep_embed(
    const float* wih0, const float* wih1, const float* wih2, const float* wih3,
    const float* whhA0, const float* whhA1, const float* whhA2, const float* whhA3,
    const float* bih0, const float* bih1, const float* bih2, const float* bih3,
    const float* bhh0, const float* bhh1, const float* bhh2, const float* bhh3,
    const float* w1, const float* b1, const float* w2, const float* b2,
    const int* __restrict__ words, const int* __restrict__ tags,
    const float* __restrict__ wemb, const float* __restrict__ temb,
    u16* __restrict__ W0a, u16* __restrict__ W1a, u16* __restrict__ WhhA,
    float* __restrict__ biasA, u16* __restrict__ W1ab, float* __restrict__ smallf,
    u16* __restrict__ XP) {
  long long idx = (long long)blockIdx.x * 256 + threadIdx.x;
  const float* wihs[4] = {wih0, wih1, wih2, wih3};
  const float* whhs[4] = {whhA0, whhA1, whhA2, whhA3};
  const float* bihs[4] = {bih0, bih1, bih2, bih3};
  const float* bhhs[4] = {bhh0, bhh1, bhh2, bhh3};
  const long long c1 = 1331200LL, c2 = 3891200LL, c3 = 6553600LL, c4 = 6560000LL,
                  c5 = 6726400LL, c6 = 6726601LL, c7 = 8365001LL;
  if (idx < c1) {                       // W0a: [2][1600][416] (pads zeroed)
    int j = (int)idx; int row = j / KPAD; int k = j - row * KPAD;
    int dir = row / G4; int ar = row - dir * G4;
    int ct = ar >> 6, rem = ar & 63, ty = rem >> 4, jj = rem & 15;
    int srow = ty * 400 + ct * 16 + jj;
    W0a[j] = (k < 400) ? f2b(wihs[dir][(size_t)srow * 400 + k]) : (u16)0;
  } else if (idx < c2) {                // W1a: [2][1600][800]
    int j = (int)(idx - c1); int row = j / 800; int k = j - row * 800;
    int dir = row / G4; int ar = row - dir * G4;
    int ct = ar >> 6, rem = ar & 63, ty = rem >> 4, jj = rem & 15;
    int srow = ty * 400 + ct * 16 + jj;
    W1a[j] = f2b(wihs[2 + dir][(size_t)srow * 800 + k]);
  } else if (idx < c3) {                // WhhA: [4][1600][416] (pads zeroed)
    int j = (int)(idx - c2); int row = j / KPAD; int k = j - row * KPAD;
    int dl = row / G4; int ar = row - dl * G4;
    int ct = ar >> 6, rem = ar & 63, ty = rem >> 4, jj = rem & 15;
    int srow = ty * 400 + ct * 16 + jj;
    WhhA[j] = (k < 400) ? f2b(whhs[dl][(size_t)srow * 400 + k]) : (u16)0;
  } else if (idx < c4) {                // biasA: [4][1600] fp32 = b_ih + b_hh
    int j = (int)(idx - c3); int dl = j / G4; int ar = j - dl * G4;
    int ct = ar >> 6, rem = ar & 63, ty = rem >> 4, jj = rem & 15;
    int srow = ty * 400 + ct * 16 + jj;
    biasA[j] = bihs[dl][srow] + bhhs[dl][srow];
  } else if (idx < c5) {                // W1ab: [208][800]
    int j = (int)(idx - c4); int row = j / 800; int k = j - row * 800;
    u16 v = 0;
    if (row < 100)      v = f2b(w1[(size_t)row * 1600 + k]);
    else if (row < 200) v = f2b(w1[(size_t)(row - 100) * 1600 + 800 + k]);
    W1ab[j] = v;
  } else if (idx < c6) {                // smallf: b1(100), w2(100), b2(1)
    int j = (int)(idx - c5);
    if (j < 100)       smallf[j] = b1[j];
    else if (j < 200)  smallf[j] = w2[j - 100];
    else               smallf[200] = b2[0];
  } else if (idx < c7) {                // embed: XP[t*128+n][d] (view(L,B,-1) bug)
    int j = (int)(idx - c6);
    int r = j / 400, d = j - r * 400;
    int t = r >> 7, n = r & 127;
    int m = n * 32 + t;                 // flat row of embeds (B,L,400)
    int b = m >> 7, l = m & 127;
    u16 v;
    if (d < 300) v = f2b(wemb[(size_t)words[b * 128 + l] * 300 + d]);
    else         v = f2b(temb[(size_t)tags[b * 128 + l] * 100 + (d - 300)]);
    XP[(size_t)r * KPAD + d] = v;       // pad cols [400,416): 0xAA poison (finite) x 0-weights = 0
  }
}

// ---------- 128x128-tile bf16 GEMM: C[M][N] = A[M][K] @ B[N][K]^T (bf16 out) ----------
__global__ __launch_bounds__(256) void gemm_bt(
    const u16* __restrict__ A, const u16* __restrict__ B, u16* __restrict__ C,
    int M, int N, int K) {
  __shared__ u16 As[128 * 40];      // pitch 40 shorts = 80B
  __shared__ u16 Bs[128 * 40];
  int tid = threadIdx.x;
  int wave = tid >> 6, lane = tid & 63;
  int m0 = blockIdx.y << 7, n0 = blockIdx.x << 7;
  int wr = wave >> 1, wc = wave & 1;
  int arow = tid >> 2, aseg = tid & 3;
  const size_t aoff0 = (size_t)(m0 + arow) * K + aseg * 8;
  const size_t aoff1 = (size_t)(m0 + 64 + arow) * K + aseg * 8;
  const size_t boff0 = (size_t)(n0 + arow) * K + aseg * 8;
  const size_t boff1 = (size_t)(n0 + 64 + arow) * K + aseg * 8;
  float4 ra0 = *(const float4*)&A[aoff0];
  float4 ra1 = *(const float4*)&A[aoff1];
  float4 rb0 = *(const float4*)&B[boff0];
  float4 rb1 = *(const float4*)&B[boff1];
  f32x4 acc[4][4] = {};
  int fr = lane & 15, fkb = (lane >> 4) * 8;
  for (int k0 = 32;; k0 += 32) {
    __syncthreads();
    *(float4*)&As[arow * 40 + aseg * 8] = ra0;
    *(float4*)&As[(64 + arow) * 40 + aseg * 8] = ra1;
    *(float4*)&Bs[arow * 40 + aseg * 8] = rb0;
    *(float4*)&Bs[(64 + arow) * 40 + aseg * 8] = rb1;
    bool more = k0 < K;
    if (more) {
      ra0 = *(const float4*)&A[aoff0 + k0];
      ra1 = *(const float4*)&A[aoff1 + k0];
      rb0 = *(const float4*)&B[boff0 + k0];
      rb1 = *(const float4*)&B[boff1 + k0];
    }
    __syncthreads();
    bf16x8 af[4], bf[4];
#pragma unroll
    for (int i = 0; i < 4; i++) af[i] = *(const bf16x8*)&As[(wr * 64 + i * 16 + fr) * 40 + fkb];
#pragma unroll
    for (int i = 0; i < 4; i++) bf[i] = *(const bf16x8*)&Bs[(wc * 64 + i * 16 + fr) * 40 + fkb];
#pragma unroll
    for (int i = 0; i < 4; i++)
#pragma unroll
      for (int j = 0; j < 4; j++)
        acc[i][j] = __builtin_amdgcn_mfma_f32_16x16x32_bf16(af[i], bf[j], acc[i][j], 0, 0, 0);
    if (!more) break;
  }
  int rg = lane >> 4;
#pragma unroll
  for (int i = 0; i < 4; i++)
#pragma unroll
    for (int j = 0; j < 4; j++)
#pragma unroll
      for (int r = 0; r < 4; r++) {
        int row = m0 + wr * 64 + i * 16 + rg * 4 + r;
        int col = n0 + wc * 64 + j * 16 + fr;
        C[(size_t)row * N + col] = f2b(acc[i][j][r]);
      }
}

// ---------- row-partitioned LSTM layer: ZERO cross-block sync ----------
// Batch rows are independent recurrence chains. Block (rowblk 0..7, dir 0..1) owns
// 16 rows x ALL 1600 arranged gates: h lives in LDS (double-buffered), c in regs,
// Whh streamed from per-XCD L2 each step. Wave w owns ctiles == w (mod 4); the 4
// type-tiles per ctile put i/f/g/o in the same lane's acc[0..3] (no transpose).
__global__ __launch_bounds__(256, 1) void lstm_layer(
    const u16* __restrict__ xg,      // [4096][3200] precomputed x-part (no bias)
    const u16* __restrict__ Whh,     // [2][1600][416] arranged (this layer)
    const float* __restrict__ bias,  // [2][1600] arranged (this layer)
    u16* __restrict__ h_cat) {       // [4096][800]
  __shared__ u16 hp[2][16 * BPITCH]; // h double buffer, 26.9 KB
  __shared__ float biasS[G4];        // 6.4 KB
  const int rb = blockIdx.x, dir = blockIdx.y;
  const int n0 = rb * 16;
  const int tid = threadIdx.x, lane = tid & 63, wave = tid >> 6;
  const int fr = lane & 15, hi = lane >> 4, fkb = hi * 8;
  const u16* wh = Whh + (size_t)dir * G4 * KPAD;
  const u16* xgd = xg + (size_t)dir * G4;

  for (int idx = tid; idx < 2 * 16 * BPITCH; idx += 256) ((u16*)hp)[idx] = 0;  // finite pads
  for (int idx = tid; idx < G4; idx += 256) biasS[idx] = bias[dir * G4 + idx];
  __syncthreads();

  float c_reg[28] = {};              // 7 ctile-iters x 4 rows
  int cur = 0;

  for (int s = 0; s < TSEQ; s++) {
    const int t = dir ? (31 - s) : s;
    bf16x8 areg[13];
    if (s > 0) {
#pragma unroll
      for (int k = 0; k < 13; k++)
        areg[k] = *(const bf16x8*)&hp[cur][fr * BPITCH + k * 32 + fkb];
    }
#pragma unroll
    for (int i = 0; i < 7; i++) {
      const int ct = wave + 4 * i;
      if (ct < 25) {
        // xg quadruples for this ctile (independent of h; in flight during MFMA)
        u16 xv[16];
#pragma unroll
        for (int r = 0; r < 4; r++) {
          const u16* p = xgd + (size_t)(t * 128 + n0 + hi * 4 + r) * XGC + ct * 64 + fr;
          xv[r * 4 + 0] = p[0];  xv[r * 4 + 1] = p[16];
          xv[r * 4 + 2] = p[32]; xv[r * 4 + 3] = p[48];
        }
        f32x4 acc[4] = {};
        if (s > 0) {
#pragma unroll
          for (int ty = 0; ty < 4; ty++) {
            const u16* wb = wh + (size_t)(ct * 64 + ty * 16 + fr) * KPAD + fkb;
#pragma unroll
            for (int k = 0; k < 13; k++) {
              bf16x8 b = *(const bf16x8*)&wb[k * 32];
              acc[ty] = __builtin_amdgcn_mfma_f32_16x16x32_bf16(areg[k], b, acc[ty], 0, 0, 0);
            }
          }
        }
        // elementwise: acc[0..3][r] = i/f/g/o for (row n0+hi*4+r, hdim ct*16+fr)
#pragma unroll
        for (int r = 0; r < 4; r++) {
          float gi = acc[0][r] + b2f(xv[r * 4 + 0]) + biasS[ct * 64 + fr];
          float gf = acc[1][r] + b2f(xv[r * 4 + 1]) + biasS[ct * 64 + 16 + fr];
          float gg = acc[2][r] + b2f(xv[r * 4 + 2]) + biasS[ct * 64 + 32 + fr];
          float go = acc[3][r] + b2f(xv[r * 4 + 3]) + biasS[ct * 64 + 48 + fr];
          float cn = sigm_(gf) * c_reg[i * 4 + r] + sigm_(gi) * tanh_(gg);
          float hn = sigm_(go) * tanh_(cn);
          c_reg[i * 4 + r] = cn;
          u16 hv = f2b(hn);
          hp[cur ^ 1][(hi * 4 + r) * BPITCH + ct * 16 + fr] = hv;
          h_cat[(size_t)(t * 128 + n0 + hi * 4 + r) * 800 + dir * HDIM + ct * 16 + fr] = hv;
        }
      }
    }
    __syncthreads();   // h[cur^1] complete; also guards next step's overwrite of hp[cur]
    cur ^= 1;
  }
}

// ---------- a/bm projection: [4096][200] = h1 @ W1ab^T, written permuted ----------
__global__ __launch_bounds__(256) void ab_gemm(
    const u16* __restrict__ h1, const u16* __restrict__ W1ab,
    const float* __restrict__ smallf, float* __restrict__ abuf, float* __restrict__ bbuf) {
  int lane = threadIdx.x & 63, wv = threadIdx.x >> 6;
  int mt = blockIdx.y * 4 + wv;
  int nt = blockIdx.x;
  int r0 = mt * 16, c0 = nt * 16;
  f32x4 acc = {};
  int fr = lane & 15, fk8 = (lane >> 4) * 8;
  for (int k0 = 0; k0 < 800; k0 += 32) {
    bf16x8 a = *(const bf16x8*)&h1[(size_t)(r0 + fr) * 800 + k0 + fk8];
    bf16x8 b = *(const bf16x8*)&W1ab[(size_t)(c0 + fr) * 800 + k0 + fk8];
    acc = __builtin_amdgcn_mfma_f32_16x16x32_bf16(a, b, acc, 0, 0, 0);
  }
  int c = c0 + fr;
  if (c < 200) {
#pragma unroll
    for (int r = 0; r < 4; r++) {
      int row = r0 + (lane >> 4) * 4 + r;
      int t = row >> 7, n = row & 127;
      int orow = n * 32 + t;
      float v = acc[r];
      if (c < 100) abuf[(size_t)orow * 100 + c] = v;
      else         bbuf[(size_t)orow * 100 + (c - 100)] = v + smallf[c - 100];
    }
  }
}

// ---------- fused pairwise MLP ----------
__global__ __launch_bounds__(256) void pairwise(
    const float* __restrict__ abuf, const float* __restrict__ bbuf,
    const float* __restrict__ smallf, float* __restrict__ outp) {
  __shared__ float aS[16 * 101];
  __shared__ float bS[16 * 101];
  __shared__ float w2S[104];
  int b = blockIdx.z, i0 = blockIdx.y * 16, j0 = blockIdx.x * 16;
  int tid = threadIdx.x;
  for (int idx = tid; idx < 1600; idx += 256) {
    int r = idx / 100, h = idx - r * 100;
    aS[r * 101 + h] = abuf[((size_t)(i0 + r) * 32 + b) * 100 + h];
    bS[r * 101 + h] = bbuf[((size_t)(j0 + r) * 32 + b) * 100 + h];
  }
  if (tid < 100) w2S[tid] = smallf[100 + tid];
  __syncthreads();
  float bias2 = smallf[200];
  int di = tid >> 4, dj = tid & 15;
  const float* ar = &aS[di * 101];
  const float* br = &bS[dj * 101];
  float s = 0.0f;
#pragma unroll 4
  for (int h = 0; h < 100; h++) s += w2S[h] * tanh_(ar[h] + br[h]);
  int i = i0 + di, j = j0 + dj;
  outp[((size_t)(i * 128 + j)) * 32 + b] = s + bias2;
}

// ---------- host ----------
extern "C" void kernel_launch(void* const* d_in, const int* in_sizes, int n_in,
                              void* d_out, int out_size, void* d_ws, size_t ws_size,
                              hipStream_t stream) {
  (void)in_sizes; (void)n_in; (void)out_size; (void)ws_size;
  const int* words = (const int*)d_in[0];
  const int* tags  = (const int*)d_in[1];
  const float* wemb = (const float*)d_in[4];
  const float* temb = (const float*)d_in[5];
  const float* wih[4] = {(const float*)d_in[6],  (const float*)d_in[10],
                         (const float*)d_in[14], (const float*)d_in[18]};
  const float* whh[4] = {(const float*)d_in[7],  (const float*)d_in[11],
                         (const float*)d_in[15], (const float*)d_in[19]};
  const float* bih[4] = {(const float*)d_in[8],  (const float*)d_in[12],
                         (const float*)d_in[16], (const float*)d_in[20]};
  const float* bhh[4] = {(const float*)d_in[9],  (const float*)d_in[13],
                         (const float*)d_in[17], (const float*)d_in[21]};
  const float* w1 = (const float*)d_in[22];
  const float* b1 = (const float*)d_in[23];
  const float* w2 = (const float*)d_in[24];
  const float* b2 = (const float*)d_in[25];
  float* out = (float*)d_out;

  char* ws = (char*)d_ws;
  size_t off = 0;
  auto alloc = [&](size_t bytes) -> void* {
    void* p = ws + off; off = (off + bytes + 255) & ~(size_t)255; return p;
  };
  float*    smallf= (float*)   alloc(201 * 4);
  float*    abuf  = (float*)   alloc((size_t)TOK * 100 * 4);
  float*    bbuf  = (float*)   alloc((size_t)TOK * 100 * 4);
  u16*      hcat0 = (u16*)     alloc((size_t)TOK * 800 * 2);
  u16*      hcat1 = (u16*)     alloc((size_t)TOK * 800 * 2);
  u16*      XP    = (u16*)     alloc((size_t)TOK * KPAD * 2);
  u16*      xg    = (u16*)     alloc((size_t)TOK * XGC * 2);          // 26.2 MB
  u16*      W0a   = (u16*)     alloc((size_t)2 * G4 * KPAD * 2);
  u16*      W1a   = (u16*)     alloc((size_t)2 * G4 * 800 * 2);
  u16*      WhhA  = (u16*)     alloc((size_t)4 * G4 * KPAD * 2);
  float*    biasA = (float*)   alloc((size_t)4 * G4 * 4);
  u16*      W1ab  = (u16*)     alloc((size_t)208 * 800 * 2);

  prep_embed<<<32677, 256, 0, stream>>>(
      wih[0], wih[1], wih[2], wih[3], whh[0], whh[1], whh[2], whh[3],
      bih[0], bih[1], bih[2], bih[3], bhh[0], bhh[1], bhh[2], bhh[3],
      w1, b1, w2, b2, words, tags, wemb, temb,
      W0a, W1a, WhhA, biasA, W1ab, smallf, XP);

  // layer 0: xg = XP @ W0a^T ; row-partitioned recurrence (no sync)
  gemm_bt<<<dim3(25, 32), 256, 0, stream>>>(XP, W0a, xg, TOK, XGC, KPAD);
  lstm_layer<<<dim3(8, 2), 256, 0, stream>>>(xg, WhhA, biasA, hcat0);

  // layer 1: xg = hcat0 @ W1a^T ; row-partitioned recurrence (no sync)
  gemm_bt<<<dim3(25, 32), 256, 0, stream>>>(hcat0, W1a, xg, TOK, XGC, 800);
  lstm_layer<<<dim3(8, 2), 256, 0, stream>>>(
      xg, WhhA + (size_t)2 * G4 * KPAD, biasA + 2 * G4, hcat1);

  ab_gemm<<<dim3(13, 64), 256, 0, stream>>>(hcat1, W1ab, smallf, abuf, bbuf);
  pairwise<<<dim3(8, 8, 32), 256, 0, stream>>>(abuf, bbuf, smallf, out);
}

// Round 14
// 417.719 us; speedup vs baseline: 8.8770x; 8.8770x over previous
//
#include <hip/hip_runtime.h>

typedef unsigned short u16;
typedef unsigned int u32;
typedef __attribute__((ext_vector_type(8))) short bf16x8;   // 8 bf16 = 4 VGPRs (MFMA A/B frag)
typedef __attribute__((ext_vector_type(4))) float f32x4;    // MFMA C/D frag
typedef __attribute__((ext_vector_type(2))) u32 u32x2;

// ---------- constants ----------
#define TSEQ 32      // LSTM time steps (reshape bug: seq runs over B)
#define NB   128     // LSTM batch
#define HDIM 400
#define KPAD 416     // 400 padded to 13*32 for MFMA K
#define G4   1600    // 4*H
#define TOK  4096    // 32*128 tokens
#define XGC  3200    // both dirs' gate cols
#define BPITCH 420   // LDS Whh pitch (shorts)

__device__ __forceinline__ float b2f(u16 u) {
  union { unsigned int i; float f; } v; v.i = ((unsigned int)u) << 16; return v.f;
}
__device__ __forceinline__ u16 f2b(float f) {
  union { float fl; unsigned int i; } v; v.fl = f;
  unsigned int r = v.i + 0x7fffu + ((v.i >> 16) & 1u);   // RNE
  return (u16)(r >> 16);
}
__device__ __forceinline__ float sigm_(float x) { return 1.0f / (1.0f + __expf(-x)); }
__device__ __forceinline__ float tanh_(float x) {
  float e = __expf(2.0f * x);
  return 1.0f - 2.0f / (e + 1.0f);   // exact limits at +-inf, no NaN
}

// MALL-coherent (cross-XCD) primitives: sc0 sc1 = bypass/write-through L2.
__device__ __forceinline__ void store_h64(u16* p, u32x2 v) {
  asm volatile("global_store_dwordx2 %0, %1, off sc0 sc1" :: "v"(p), "v"(v) : "memory");
}
__device__ __forceinline__ void store_flag(unsigned* p, unsigned v) {
  asm volatile("global_store_dword %0, %1, off sc0 sc1" :: "v"(p), "v"(v) : "memory");
}
__device__ __forceinline__ unsigned poll_cnt(const unsigned* p) {
  unsigned v;
  asm volatile("global_load_dword %0, %1, off sc0 sc1\n\ts_waitcnt vmcnt(0)"
               : "=v"(v) : "v"(p) : "memory");
  return v;
}

// ---------- fused weight prep + embedding (inputs fp32, verified) ----------
// arranged gate row: ar = ctile*64 + type*16 + j  <->  orig row = type*400 + ctile*16 + j
__global__ __launch_bounds__(256) void prep_embed(
    const float* wih0, const float* wih1, const float* wih2, const float* wih3,
    const float* whhA0, const float* whhA1, const float* whhA2, const float* whhA3,
    const float* bih0, const float* bih1, const float* bih2, const float* bih3,
    const float* bhh0, const float* bhh1, const float* bhh2, const float* bhh3,
    const float* w1, const float* b1, const float* w2, const float* b2,
    const int* __restrict__ words, const int* __restrict__ tags,
    const float* __restrict__ wemb, const float* __restrict__ temb,
    u16* __restrict__ W0a, u16* __restrict__ W1a, u16* __restrict__ WhhA,
    float* __restrict__ biasA, u16* __restrict__ W1ab, float* __restrict__ smallf,
    u16* __restrict__ XP) {
  long long idx = (long long)blockIdx.x * 256 + threadIdx.x;
  const float* wihs[4] = {wih0, wih1, wih2, wih3};
  const float* whhs[4] = {whhA0, whhA1, whhA2, whhA3};
  const float* bihs[4] = {bih0, bih1, bih2, bih3};
  const float* bhhs[4] = {bhh0, bhh1, bhh2, bhh3};
  const long long c1 = 1331200LL, c2 = 3891200LL, c3 = 6553600LL, c4 = 6560000LL,
                  c5 = 6726400LL, c6 = 6726601LL, c7 = 8365001LL;
  if (idx < c1) {                       // W0a: [2][1600][416] (pads zeroed)
    int j = (int)idx; int row = j / KPAD; int k = j - row * KPAD;
    int dir = row / G4; int ar = row - dir * G4;
    int ct = ar >> 6, rem = ar & 63, ty = rem >> 4, jj = rem & 15;
    int srow = ty * 400 + ct * 16 + jj;
    W0a[j] = (k < 400) ? f2b(wihs[dir][(size_t)srow * 400 + k]) : (u16)0;
  } else if (idx < c2) {                // W1a: [2][1600][800]
    int j = (int)(idx - c1); int row = j / 800; int k = j - row * 800;
    int dir = row / G4; int ar = row - dir * G4;
    int ct = ar >> 6, rem = ar & 63, ty = rem >> 4, jj = rem & 15;
    int srow = ty * 400 + ct * 16 + jj;
    W1a[j] = f2b(wihs[2 + dir][(size_t)srow * 800 + k]);
  } else if (idx < c3) {                // WhhA: [4][1600][416] (pads zeroed)
    int j = (int)(idx - c2); int row = j / KPAD; int k = j - row * KPAD;
    int dl = row / G4; int ar = row - dl * G4;
    int ct = ar >> 6, rem = ar & 63, ty = rem >> 4, jj = rem & 15;
    int srow = ty * 400 + ct * 16 + jj;
    WhhA[j] = (k < 400) ? f2b(whhs[dl][(size_t)srow * 400 + k]) : (u16)0;
  } else if (idx < c4) {                // biasA: [4][1600] fp32 = b_ih + b_hh
    int j = (int)(idx - c3); int dl = j / G4; int ar = j - dl * G4;
    int ct = ar >> 6, rem = ar & 63, ty = rem >> 4, jj = rem & 15;
    int srow = ty * 400 + ct * 16 + jj;
    biasA[j] = bihs[dl][srow] + bhhs[dl][srow];
  } else if (idx < c5) {                // W1ab: [208][800]
    int j = (int)(idx - c4); int row = j / 800; int k = j - row * 800;
    u16 v = 0;
    if (row < 100)      v = f2b(w1[(size_t)row * 1600 + k]);
    else if (row < 200) v = f2b(w1[(size_t)(row - 100) * 1600 + 800 + k]);
    W1ab[j] = v;
  } else if (idx < c6) {                // smallf: b1(100), w2(100), b2(1)
    int j = (int)(idx - c5);
    if (j < 100)       smallf[j] = b1[j];
    else if (j < 200)  smallf[j] = w2[j - 100];
    else               smallf[200] = b2[0];
  } else if (idx < c7) {                // embed: XP[t*128+n][d] (view(L,B,-1) bug)
    int j = (int)(idx - c6);
    int r = j / 400, d = j - r * 400;
    int t = r >> 7, n = r & 127;
    int m = n * 32 + t;                 // flat row of embeds (B,L,400)
    int b = m >> 7, l = m & 127;
    u16 v;
    if (d < 300) v = f2b(wemb[(size_t)words[b * 128 + l] * 300 + d]);
    else         v = f2b(temb[(size_t)tags[b * 128 + l] * 100 + (d - 300)]);
    XP[(size_t)r * KPAD + d] = v;       // pad cols [400,416): poison x 0-weights = 0
  }
}

// ---------- 128x128-tile bf16 GEMM: C[M][N] = A[M][K] @ B[N][K]^T (bf16 out) ----------
__global__ __launch_bounds__(256) void gemm_bt(
    const u16* __restrict__ A, const u16* __restrict__ B, u16* __restrict__ C,
    int M, int N, int K) {
  __shared__ u16 As[128 * 40];      // pitch 40 shorts = 80B
  __shared__ u16 Bs[128 * 40];
  int tid = threadIdx.x;
  int wave = tid >> 6, lane = tid & 63;
  int m0 = blockIdx.y << 7, n0 = blockIdx.x << 7;
  int wr = wave >> 1, wc = wave & 1;
  int arow = tid >> 2, aseg = tid & 3;
  const size_t aoff0 = (size_t)(m0 + arow) * K + aseg * 8;
  const size_t aoff1 = (size_t)(m0 + 64 + arow) * K + aseg * 8;
  const size_t boff0 = (size_t)(n0 + arow) * K + aseg * 8;
  const size_t boff1 = (size_t)(n0 + 64 + arow) * K + aseg * 8;
  float4 ra0 = *(const float4*)&A[aoff0];
  float4 ra1 = *(const float4*)&A[aoff1];
  float4 rb0 = *(const float4*)&B[boff0];
  float4 rb1 = *(const float4*)&B[boff1];
  f32x4 acc[4][4] = {};
  int fr = lane & 15, fkb = (lane >> 4) * 8;
  for (int k0 = 32;; k0 += 32) {
    __syncthreads();
    *(float4*)&As[arow * 40 + aseg * 8] = ra0;
    *(float4*)&As[(64 + arow) * 40 + aseg * 8] = ra1;
    *(float4*)&Bs[arow * 40 + aseg * 8] = rb0;
    *(float4*)&Bs[(64 + arow) * 40 + aseg * 8] = rb1;
    bool more = k0 < K;
    if (more) {
      ra0 = *(const float4*)&A[aoff0 + k0];
      ra1 = *(const float4*)&A[aoff1 + k0];
      rb0 = *(const float4*)&B[boff0 + k0];
      rb1 = *(const float4*)&B[boff1 + k0];
    }
    __syncthreads();
    bf16x8 af[4], bf[4];
#pragma unroll
    for (int i = 0; i < 4; i++) af[i] = *(const bf16x8*)&As[(wr * 64 + i * 16 + fr) * 40 + fkb];
#pragma unroll
    for (int i = 0; i < 4; i++) bf[i] = *(const bf16x8*)&Bs[(wc * 64 + i * 16 + fr) * 40 + fkb];
#pragma unroll
    for (int i = 0; i < 4; i++)
#pragma unroll
      for (int j = 0; j < 4; j++)
        acc[i][j] = __builtin_amdgcn_mfma_f32_16x16x32_bf16(af[i], bf[j], acc[i][j], 0, 0, 0);
    if (!more) break;
  }
  int rg = lane >> 4;
#pragma unroll
  for (int i = 0; i < 4; i++)
#pragma unroll
    for (int j = 0; j < 4; j++)
#pragma unroll
      for (int r = 0; r < 4; r++) {
        int row = m0 + wr * 64 + i * 16 + rg * 4 + r;
        int col = n0 + wc * 64 + j * 16 + fr;
        C[(size_t)row * N + col] = f2b(acc[i][j][r]);
      }
}

// ---------- persistent LSTM layer (r12 protocol, swapped-operand mapping) ----------
// Block (ctile 0..24, ntile 0..1, dir 0..1). MFMA computed as C[gate][row]:
// A = Whh tile (LDS), B = h frag (global). C: col=lane&15=batch row, row=hi*4+r=
// h-dim within ctile -> each lane owns ONE row x 4 consecutive h-dims: h-store is
// one 8B dwordx2, xg prefetch is 4x ushort4. Same MFMA sum order => bit-identical.
__global__ __launch_bounds__(256, 1) void lstm_persist(
    const u16* __restrict__ xg,      // [4096][3200] precomputed x-part (no bias)
    const u16* __restrict__ Whh,     // [2][1600][416] arranged (this layer)
    const float* __restrict__ bias,  // [2][1600] arranged (this layer)
    u16* __restrict__ hA,            // [2][128][416] ping (pads: junk x 0-weights)
    u16* __restrict__ hB,            // pong
    u16* __restrict__ h_cat,         // [4096][800]
    unsigned* __restrict__ flags) {  // [4 groups][32] zeroed
  __shared__ u16 Bs[64 * BPITCH];    // 53760 B
  __shared__ float biasS[64];
  const int ctile = blockIdx.x, ntile = blockIdx.y, dir = blockIdx.z;
  const int n0 = ntile * 64, ar0 = ctile * 64;
  const int tid = threadIdx.x, lane = tid & 63, wave = tid >> 6;
  const int fr = lane & 15, hi = lane >> 4, fkb = hi * 8;
  unsigned* flagbase = flags + (dir * 2 + ntile) * 32;

  const u16* wbase = Whh + ((size_t)dir * G4 + ar0) * KPAD;
  for (int idx = tid; idx < 64 * 52; idx += 256) {
    int r = idx / 52, kk = (idx - r * 52) * 8;
    *(float4*)&Bs[r * BPITCH + kk] = *(const float4*)&wbase[(size_t)r * KPAD + kk];
  }
  if (tid < 64) biasS[tid] = bias[dir * G4 + ar0 + tid];
  __syncthreads();

  const u16* hin = hA;
  u16* hout = hB;
  float c_reg[4] = {0.f, 0.f, 0.f, 0.f};       // h-dims hi*4..+3 of row arow
  const int arow = n0 + wave * 16 + fr;        // this lane's batch row (A & C & store)
  const int hd0 = ctile * 16 + hi * 4;         // first of this lane's 4 h-dims

  // xv prefetch for step 0: 4x ushort4 from row arow
  u16 xv[16];
  {
    const int t0 = dir ? 31 : 0;
    const u16* xr = xg + (size_t)(t0 * 128 + arow) * XGC + dir * G4 + ar0 + hi * 4;
#pragma unroll
    for (int ty = 0; ty < 4; ty++)
      *(u32x2*)&xv[ty * 4] = *(const u32x2*)&xr[ty * 16];
  }

  for (int s = 0; s < TSEQ; s++) {
    const int t = dir ? (31 - s) : s;
    f32x4 acc[4] = {};
    if (s > 0) {
      // throttled per-lane poll of the 25 producer flags, then re-align block
      if (tid < 25) {
        const unsigned tgt = (unsigned)s;
        while (poll_cnt(&flagbase[tid]) < tgt) __builtin_amdgcn_s_sleep(1);
      }
      __syncthreads();
      // h loads (MALL-coherent), one drain, MFMA (A = Whh from LDS, B = h)
      const u16* hb = hin + ((size_t)dir * NB + arow) * KPAD + fkb;
      bf16x8 areg[13];
#pragma unroll
      for (int k = 0; k < 13; k++) {
        const u16* p = hb + k * 32;
        asm volatile("global_load_dwordx4 %0, %1, off sc0 sc1" : "=v"(areg[k]) : "v"(p));
      }
      asm volatile("s_waitcnt vmcnt(0)" ::: "memory");
      __builtin_amdgcn_sched_barrier(0);
#pragma unroll
      for (int k = 0; k < 13; k++) {
#pragma unroll
        for (int ty = 0; ty < 4; ty++) {
          bf16x8 a = *(const bf16x8*)&Bs[(ty * 16 + fr) * BPITCH + k * 32 + fkb];
          acc[ty] = __builtin_amdgcn_mfma_f32_16x16x32_bf16(a, areg[k], acc[ty], 0, 0, 0);
        }
      }
    }
    // elementwise: acc[ty][r] = gate ty for (row arow, h-dim hd0+r)
    u16 hvals[4];
#pragma unroll
    for (int r = 0; r < 4; r++) {
      float gi = acc[0][r] + b2f(xv[r])      + biasS[hi * 4 + r];
      float gf = acc[1][r] + b2f(xv[4 + r])  + biasS[16 + hi * 4 + r];
      float gg = acc[2][r] + b2f(xv[8 + r])  + biasS[32 + hi * 4 + r];
      float go = acc[3][r] + b2f(xv[12 + r]) + biasS[48 + hi * 4 + r];
      float c_new = sigm_(gf) * c_reg[r] + sigm_(gi) * tanh_(gg);
      float h_new = sigm_(go) * tanh_(c_new);
      c_reg[r] = c_new;
      hvals[r] = f2b(h_new);
    }
    {
      u32x2 packed;
      packed.x = (u32)hvals[0] | ((u32)hvals[1] << 16);
      packed.y = (u32)hvals[2] | ((u32)hvals[3] << 16);
      store_h64(&hout[((size_t)dir * NB + arow) * KPAD + hd0], packed);
      // drain h stores, block-wide order, then signal
      asm volatile("s_waitcnt vmcnt(0)" ::: "memory");
      __syncthreads();
      if (tid == 0) store_flag(&flagbase[ctile], (unsigned)(s + 1));
      // next-step xg prefetch first, then h_cat (both overlap peers' waits)
      const int sn = (s < 31) ? (s + 1) : 31;
      const int tn = dir ? (31 - sn) : sn;
      const u16* xr = xg + (size_t)(tn * 128 + arow) * XGC + dir * G4 + ar0 + hi * 4;
#pragma unroll
      for (int ty = 0; ty < 4; ty++)
        *(u32x2*)&xv[ty * 4] = *(const u32x2*)&xr[ty * 16];
      *(u32x2*)&h_cat[(size_t)(t * 128 + arow) * 800 + dir * HDIM + hd0] = packed;
    }
    u16* tmp = (u16*)hin; hin = hout; hout = tmp;
  }
}

// ---------- a/bm projection: [4096][200] = h1 @ W1ab^T, written permuted ----------
__global__ __launch_bounds__(256) void ab_gemm(
    const u16* __restrict__ h1, const u16* __restrict__ W1ab,
    const float* __restrict__ smallf, float* __restrict__ abuf, float* __restrict__ bbuf) {
  int lane = threadIdx.x & 63, wv = threadIdx.x >> 6;
  int mt = blockIdx.y * 4 + wv;
  int nt = blockIdx.x;
  int r0 = mt * 16, c0 = nt * 16;
  f32x4 acc = {};
  int fr = lane & 15, fk8 = (lane >> 4) * 8;
  for (int k0 = 0; k0 < 800; k0 += 32) {
    bf16x8 a = *(const bf16x8*)&h1[(size_t)(r0 + fr) * 800 + k0 + fk8];
    bf16x8 b = *(const bf16x8*)&W1ab[(size_t)(c0 + fr) * 800 + k0 + fk8];
    acc = __builtin_amdgcn_mfma_f32_16x16x32_bf16(a, b, acc, 0, 0, 0);
  }
  int c = c0 + fr;
  if (c < 200) {
#pragma unroll
    for (int r = 0; r < 4; r++) {
      int row = r0 + (lane >> 4) * 4 + r;
      int t = row >> 7, n = row & 127;
      int orow = n * 32 + t;
      float v = acc[r];
      if (c < 100) abuf[(size_t)orow * 100 + c] = v;
      else         bbuf[(size_t)orow * 100 + (c - 100)] = v + smallf[c - 100];
    }
  }
}

// ---------- fused pairwise MLP ----------
__global__ __launch_bounds__(256) void pairwise(
    const float* __restrict__ abuf, const float* __restrict__ bbuf,
    const float* __restrict__ smallf, float* __restrict__ outp) {
  __shared__ float aS[16 * 101];
  __shared__ float bS[16 * 101];
  __shared__ float w2S[104];
  int b = blockIdx.z, i0 = blockIdx.y * 16, j0 = blockIdx.x * 16;
  int tid = threadIdx.x;
  for (int idx = tid; idx < 1600; idx += 256) {
    int r = idx / 100, h = idx - r * 100;
    aS[r * 101 + h] = abuf[((size_t)(i0 + r) * 32 + b) * 100 + h];
    bS[r * 101 + h] = bbuf[((size_t)(j0 + r) * 32 + b) * 100 + h];
  }
  if (tid < 100) w2S[tid] = smallf[100 + tid];
  __syncthreads();
  float bias2 = smallf[200];
  int di = tid >> 4, dj = tid & 15;
  const float* ar = &aS[di * 101];
  const float* br = &bS[dj * 101];
  float s = 0.0f;
#pragma unroll 4
  for (int h = 0; h < 100; h++) s += w2S[h] * tanh_(ar[h] + br[h]);
  int i = i0 + di, j = j0 + dj;
  outp[((size_t)(i * 128 + j)) * 32 + b] = s + bias2;
}

// ---------- host ----------
extern "C" void kernel_launch(void* const* d_in, const int* in_sizes, int n_in,
                              void* d_out, int out_size, void* d_ws, size_t ws_size,
                              hipStream_t stream) {
  (void)in_sizes; (void)n_in; (void)out_size; (void)ws_size;
  const int* words = (const int*)d_in[0];
  const int* tags  = (const int*)d_in[1];
  const float* wemb = (const float*)d_in[4];
  const float* temb = (const float*)d_in[5];
  const float* wih[4] = {(const float*)d_in[6],  (const float*)d_in[10],
                         (const float*)d_in[14], (const float*)d_in[18]};
  const float* whh[4] = {(const float*)d_in[7],  (const float*)d_in[11],
                         (const float*)d_in[15], (const float*)d_in[19]};
  const float* bih[4] = {(const float*)d_in[8],  (const float*)d_in[12],
                         (const float*)d_in[16], (const float*)d_in[20]};
  const float* bhh[4] = {(const float*)d_in[9],  (const float*)d_in[13],
                         (const float*)d_in[17], (const float*)d_in[21]};
  const float* w1 = (const float*)d_in[22];
  const float* b1 = (const float*)d_in[23];
  const float* w2 = (const float*)d_in[24];
  const float* b2 = (const float*)d_in[25];
  float* out = (float*)d_out;

  char* ws = (char*)d_ws;
  size_t off = 0;
  auto alloc = [&](size_t bytes) -> void* {
    void* p = ws + off; off = (off + bytes + 255) & ~(size_t)255; return p;
  };
  u16*      hstate= (u16*)     alloc((size_t)2 * 2 * NB * KPAD * 2);  // ping+pong (never memset)
  unsigned* flags = (unsigned*)alloc(1024);                           // 2 layers x 4 groups x 32
  float*    smallf= (float*)   alloc(201 * 4);
  float*    abuf  = (float*)   alloc((size_t)TOK * 100 * 4);
  float*    bbuf  = (float*)   alloc((size_t)TOK * 100 * 4);
  u16*      hcat0 = (u16*)     alloc((size_t)TOK * 800 * 2);
  u16*      hcat1 = (u16*)     alloc((size_t)TOK * 800 * 2);
  u16*      XP    = (u16*)     alloc((size_t)TOK * KPAD * 2);
  u16*      xg    = (u16*)     alloc((size_t)TOK * XGC * 2);          // 26.2 MB
  u16*      W0a   = (u16*)     alloc((size_t)2 * G4 * KPAD * 2);
  u16*      W1a   = (u16*)     alloc((size_t)2 * G4 * 800 * 2);
  u16*      WhhA  = (u16*)     alloc((size_t)4 * G4 * KPAD * 2);
  float*    biasA = (float*)   alloc((size_t)4 * G4 * 4);
  u16*      W1ab  = (u16*)     alloc((size_t)208 * 800 * 2);

  u16* h0 = hstate;
  u16* h1 = hstate + (size_t)2 * NB * KPAD;

  (void)hipMemsetAsync(flags, 0, 1024, stream);              // only required memset
  prep_embed<<<32677, 256, 0, stream>>>(
      wih[0], wih[1], wih[2], wih[3], whh[0], whh[1], whh[2], whh[3],
      bih[0], bih[1], bih[2], bih[3], bhh[0], bhh[1], bhh[2], bhh[3],
      w1, b1, w2, b2, words, tags, wemb, temb,
      W0a, W1a, WhhA, biasA, W1ab, smallf, XP);

  // layer 0: xg = XP @ W0a^T ; persistent recurrence
  gemm_bt<<<dim3(25, 32), 256, 0, stream>>>(XP, W0a, xg, TOK, XGC, KPAD);
  lstm_persist<<<dim3(25, 2, 2), 256, 0, stream>>>(
      xg, WhhA, biasA, h0, h1, hcat0, flags);

  // layer 1: xg = hcat0 @ W1a^T ; persistent recurrence
  gemm_bt<<<dim3(25, 32), 256, 0, stream>>>(hcat0, W1a, xg, TOK, XGC, 800);
  lstm_persist<<<dim3(25, 2, 2), 256, 0, stream>>>(
      xg, WhhA + (size_t)2 * G4 * KPAD, biasA + 2 * G4, h0, h1, hcat1, flags + 128);

  ab_gemm<<<dim3(13, 64), 256, 0, stream>>>(hcat1, W1ab, smallf, abuf, bbuf);
  pairwise<<<dim3(8, 8, 32), 256, 0, stream>>>(abuf, bbuf, smallf, out);
}

// Round 16
// 416.980 us; speedup vs baseline: 8.8927x; 1.0018x over previous
//
#include <hip/hip_runtime.h>

typedef unsigned short u16;
typedef unsigned int u32;
typedef __attribute__((ext_vector_type(8))) short bf16x8;   // 8 bf16 = 4 VGPRs (MFMA A/B frag)
typedef __attribute__((ext_vector_type(4))) float f32x4;    // MFMA C/D frag
typedef __attribute__((ext_vector_type(2))) u32 u32x2;

// ---------- constants ----------
#define TSEQ 32      // LSTM time steps (reshape bug: seq runs over B)
#define NB   128     // LSTM batch
#define HDIM 400
#define KPAD 416     // 400 padded to 13*32 for MFMA K
#define G4   1600    // 4*H
#define TOK  4096    // 32*128 tokens
#define XGC  3200    // both dirs' gate cols
#define BPITCH 420   // LDS Whh pitch (shorts)

__device__ __forceinline__ float b2f(u16 u) {
  union { unsigned int i; float f; } v; v.i = ((unsigned int)u) << 16; return v.f;
}
__device__ __forceinline__ u16 f2b(float f) {
  union { float fl; unsigned int i; } v; v.fl = f;
  unsigned int r = v.i + 0x7fffu + ((v.i >> 16) & 1u);   // RNE
  return (u16)(r >> 16);
}
__device__ __forceinline__ float sigm_(float x) { return 1.0f / (1.0f + __expf(-x)); }
__device__ __forceinline__ float tanh_(float x) {
  float e = __expf(2.0f * x);
  return 1.0f - 2.0f / (e + 1.0f);   // exact limits at +-inf, no NaN
}

// MALL-coherent (cross-XCD) primitives: sc0 sc1 = bypass/write-through L2.
// NOTE (r15 lesson): sc0 WITHOUT sc1 is CU-scope on gfx950 -> cross-CU polling
// deadlocks on stale cached lines. All cross-block exchange must use sc0 sc1.
__device__ __forceinline__ void store_h64(u16* p, u32x2 v) {
  asm volatile("global_store_dwordx2 %0, %1, off sc0 sc1" :: "v"(p), "v"(v) : "memory");
}
__device__ __forceinline__ void store_flag(unsigned* p, unsigned v) {
  asm volatile("global_store_dword %0, %1, off sc0 sc1" :: "v"(p), "v"(v) : "memory");
}
__device__ __forceinline__ unsigned poll_cnt(const unsigned* p) {
  unsigned v;
  asm volatile("global_load_dword %0, %1, off sc0 sc1\n\ts_waitcnt vmcnt(0)"
               : "=v"(v) : "v"(p) : "memory");
  return v;
}

// ---------- fused weight prep + embedding (inputs fp32, verified) ----------
// arranged gate row: ar = ctile*64 + type*16 + j  <->  orig row = type*400 + ctile*16 + j
__global__ __launch_bounds__(256) void prep_embed(
    const float* wih0, const float* wih1, const float* wih2, const float* wih3,
    const float* whhA0, const float* whhA1, const float* whhA2, const float* whhA3,
    const float* bih0, const float* bih1, const float* bih2, const float* bih3,
    const float* bhh0, const float* bhh1, const float* bhh2, const float* bhh3,
    const float* w1, const float* b1, const float* w2, const float* b2,
    const int* __restrict__ words, const int* __restrict__ tags,
    const float* __restrict__ wemb, const float* __restrict__ temb,
    u16* __restrict__ W0a, u16* __restrict__ W1a, u16* __restrict__ WhhA,
    float* __restrict__ biasA, u16* __restrict__ W1ab, float* __restrict__ smallf,
    u16* __restrict__ XP) {
  long long idx = (long long)blockIdx.x * 256 + threadIdx.x;
  const float* wihs[4] = {wih0, wih1, wih2, wih3};
  const float* whhs[4] = {whhA0, whhA1, whhA2, whhA3};
  const float* bihs[4] = {bih0, bih1, bih2, bih3};
  const float* bhhs[4] = {bhh0, bhh1, bhh2, bhh3};
  const long long c1 = 1331200LL, c2 = 3891200LL, c3 = 6553600LL, c4 = 6560000LL,
                  c5 = 6726400LL, c6 = 6726601LL, c7 = 8365001LL;
  if (idx < c1) {                       // W0a: [2][1600][416] (pads zeroed)
    int j = (int)idx; int row = j / KPAD; int k = j - row * KPAD;
    int dir = row / G4; int ar = row - dir * G4;
    int ct = ar >> 6, rem = ar & 63, ty = rem >> 4, jj = rem & 15;
    int srow = ty * 400 + ct * 16 + jj;
    W0a[j] = (k < 400) ? f2b(wihs[dir][(size_t)srow * 400 + k]) : (u16)0;
  } else if (idx < c2) {                // W1a: [2][1600][800]
    int j = (int)(idx - c1); int row = j / 800; int k = j - row * 800;
    int dir = row / G4; int ar = row - dir * G4;
    int ct = ar >> 6, rem = ar & 63, ty = rem >> 4, jj = rem & 15;
    int srow = ty * 400 + ct * 16 + jj;
    W1a[j] = f2b(wihs[2 + dir][(size_t)srow * 800 + k]);
  } else if (idx < c3) {                // WhhA: [4][1600][416] (pads zeroed)
    int j = (int)(idx - c2); int row = j / KPAD; int k = j - row * KPAD;
    int dl = row / G4; int ar = row - dl * G4;
    int ct = ar >> 6, rem = ar & 63, ty = rem >> 4, jj = rem & 15;
    int srow = ty * 400 + ct * 16 + jj;
    WhhA[j] = (k < 400) ? f2b(whhs[dl][(size_t)srow * 400 + k]) : (u16)0;
  } else if (idx < c4) {                // biasA: [4][1600] fp32 = b_ih + b_hh
    int j = (int)(idx - c3); int dl = j / G4; int ar = j - dl * G4;
    int ct = ar >> 6, rem = ar & 63, ty = rem >> 4, jj = rem & 15;
    int srow = ty * 400 + ct * 16 + jj;
    biasA[j] = bihs[dl][srow] + bhhs[dl][srow];
  } else if (idx < c5) {                // W1ab: [208][800]
    int j = (int)(idx - c4); int row = j / 800; int k = j - row * 800;
    u16 v = 0;
    if (row < 100)      v = f2b(w1[(size_t)row * 1600 + k]);
    else if (row < 200) v = f2b(w1[(size_t)(row - 100) * 1600 + 800 + k]);
    W1ab[j] = v;
  } else if (idx < c6) {                // smallf: b1(100), w2(100), b2(1)
    int j = (int)(idx - c5);
    if (j < 100)       smallf[j] = b1[j];
    else if (j < 200)  smallf[j] = w2[j - 100];
    else               smallf[200] = b2[0];
  } else if (idx < c7) {                // embed: XP[t*128+n][d] (view(L,B,-1) bug)
    int j = (int)(idx - c6);
    int r = j / 400, d = j - r * 400;
    int t = r >> 7, n = r & 127;
    int m = n * 32 + t;                 // flat row of embeds (B,L,400)
    int b = m >> 7, l = m & 127;
    u16 v;
    if (d < 300) v = f2b(wemb[(size_t)words[b * 128 + l] * 300 + d]);
    else         v = f2b(temb[(size_t)tags[b * 128 + l] * 100 + (d - 300)]);
    XP[(size_t)r * KPAD + d] = v;       // pad cols [400,416): poison x 0-weights = 0
  }
}

// ---------- 128x128-tile bf16 GEMM: C[M][N] = A[M][K] @ B[N][K]^T (bf16 out) ----------
__global__ __launch_bounds__(256) void gemm_bt(
    const u16* __restrict__ A, const u16* __restrict__ B, u16* __restrict__ C,
    int M, int N, int K) {
  __shared__ u16 As[128 * 40];      // pitch 40 shorts = 80B
  __shared__ u16 Bs[128 * 40];
  int tid = threadIdx.x;
  int wave = tid >> 6, lane = tid & 63;
  int m0 = blockIdx.y << 7, n0 = blockIdx.x << 7;
  int wr = wave >> 1, wc = wave & 1;
  int arow = tid >> 2, aseg = tid & 3;
  const size_t aoff0 = (size_t)(m0 + arow) * K + aseg * 8;
  const size_t aoff1 = (size_t)(m0 + 64 + arow) * K + aseg * 8;
  const size_t boff0 = (size_t)(n0 + arow) * K + aseg * 8;
  const size_t boff1 = (size_t)(n0 + 64 + arow) * K + aseg * 8;
  float4 ra0 = *(const float4*)&A[aoff0];
  float4 ra1 = *(const float4*)&A[aoff1];
  float4 rb0 = *(const float4*)&B[boff0];
  float4 rb1 = *(const float4*)&B[boff1];
  f32x4 acc[4][4] = {};
  int fr = lane & 15, fkb = (lane >> 4) * 8;
  for (int k0 = 32;; k0 += 32) {
    __syncthreads();
    *(float4*)&As[arow * 40 + aseg * 8] = ra0;
    *(float4*)&As[(64 + arow) * 40 + aseg * 8] = ra1;
    *(float4*)&Bs[arow * 40 + aseg * 8] = rb0;
    *(float4*)&Bs[(64 + arow) * 40 + aseg * 8] = rb1;
    bool more = k0 < K;
    if (more) {
      ra0 = *(const float4*)&A[aoff0 + k0];
      ra1 = *(const float4*)&A[aoff1 + k0];
      rb0 = *(const float4*)&B[boff0 + k0];
      rb1 = *(const float4*)&B[boff1 + k0];
    }
    __syncthreads();
    bf16x8 af[4], bf[4];
#pragma unroll
    for (int i = 0; i < 4; i++) af[i] = *(const bf16x8*)&As[(wr * 64 + i * 16 + fr) * 40 + fkb];
#pragma unroll
    for (int i = 0; i < 4; i++) bf[i] = *(const bf16x8*)&Bs[(wc * 64 + i * 16 + fr) * 40 + fkb];
#pragma unroll
    for (int i = 0; i < 4; i++)
#pragma unroll
      for (int j = 0; j < 4; j++)
        acc[i][j] = __builtin_amdgcn_mfma_f32_16x16x32_bf16(af[i], bf[j], acc[i][j], 0, 0, 0);
    if (!more) break;
  }
  int rg = lane >> 4;
#pragma unroll
  for (int i = 0; i < 4; i++)
#pragma unroll
    for (int j = 0; j < 4; j++)
#pragma unroll
      for (int r = 0; r < 4; r++) {
        int row = m0 + wr * 64 + i * 16 + rg * 4 + r;
        int col = n0 + wc * 64 + j * 16 + fr;
        C[(size_t)row * N + col] = f2b(acc[i][j][r]);
      }
}

// ---------- persistent LSTM layer (r14-proven: drain+flag+throttled poll) ----------
// Block (ctile 0..24, ntile 0..1, dir 0..1). MFMA computed as C[gate][row]:
// A = Whh tile (LDS), B = h frag (global). C: col=lane&15=batch row, row=hi*4+r=
// h-dim within ctile -> each lane owns ONE row x 4 consecutive h-dims: h-store is
// one 8B dwordx2, xg prefetch is 4x ushort4.
__global__ __launch_bounds__(256, 1) void lstm_persist(
    const u16* __restrict__ xg,      // [4096][3200] precomputed x-part (no bias)
    const u16* __restrict__ Whh,     // [2][1600][416] arranged (this layer)
    const float* __restrict__ bias,  // [2][1600] arranged (this layer)
    u16* __restrict__ hA,            // [2][128][416] ping (pads: junk x 0-weights)
    u16* __restrict__ hB,            // pong
    u16* __restrict__ h_cat,         // [4096][800]
    unsigned* __restrict__ flags) {  // [4 groups][32] zeroed
  __shared__ u16 Bs[64 * BPITCH];    // 53760 B
  __shared__ float biasS[64];
  const int ctile = blockIdx.x, ntile = blockIdx.y, dir = blockIdx.z;
  const int n0 = ntile * 64, ar0 = ctile * 64;
  const int tid = threadIdx.x, lane = tid & 63, wave = tid >> 6;
  const int fr = lane & 15, hi = lane >> 4, fkb = hi * 8;
  unsigned* flagbase = flags + (dir * 2 + ntile) * 32;

  const u16* wbase = Whh + ((size_t)dir * G4 + ar0) * KPAD;
  for (int idx = tid; idx < 64 * 52; idx += 256) {
    int r = idx / 52, kk = (idx - r * 52) * 8;
    *(float4*)&Bs[r * BPITCH + kk] = *(const float4*)&wbase[(size_t)r * KPAD + kk];
  }
  if (tid < 64) biasS[tid] = bias[dir * G4 + ar0 + tid];
  __syncthreads();

  const u16* hin = hA;
  u16* hout = hB;
  float c_reg[4] = {0.f, 0.f, 0.f, 0.f};       // h-dims hd0..+3 of row arow
  const int arow = n0 + wave * 16 + fr;        // this lane's batch row (A & C & store)
  const int hd0 = ctile * 16 + hi * 4;         // first of this lane's 4 h-dims

  // xv prefetch for step 0: 4x ushort4 from row arow
  u16 xv[16];
  {
    const int t0 = dir ? 31 : 0;
    const u16* xr = xg + (size_t)(t0 * 128 + arow) * XGC + dir * G4 + ar0 + hi * 4;
#pragma unroll
    for (int ty = 0; ty < 4; ty++)
      *(u32x2*)&xv[ty * 4] = *(const u32x2*)&xr[ty * 16];
  }

  for (int s = 0; s < TSEQ; s++) {
    const int t = dir ? (31 - s) : s;
    f32x4 acc[4] = {};
    if (s > 0) {
      // throttled per-lane poll of the 25 producer flags, then re-align block
      if (tid < 25) {
        const unsigned tgt = (unsigned)s;
        while (poll_cnt(&flagbase[tid]) < tgt) __builtin_amdgcn_s_sleep(1);
      }
      __syncthreads();
      // h loads (MALL-coherent), one drain, MFMA (A = Whh from LDS, B = h)
      const u16* hb = hin + ((size_t)dir * NB + arow) * KPAD + fkb;
      bf16x8 areg[13];
#pragma unroll
      for (int k = 0; k < 13; k++) {
        const u16* p = hb + k * 32;
        asm volatile("global_load_dwordx4 %0, %1, off sc0 sc1" : "=v"(areg[k]) : "v"(p));
      }
      asm volatile("s_waitcnt vmcnt(0)" ::: "memory");
      __builtin_amdgcn_sched_barrier(0);
#pragma unroll
      for (int k = 0; k < 13; k++) {
#pragma unroll
        for (int ty = 0; ty < 4; ty++) {
          bf16x8 a = *(const bf16x8*)&Bs[(ty * 16 + fr) * BPITCH + k * 32 + fkb];
          acc[ty] = __builtin_amdgcn_mfma_f32_16x16x32_bf16(a, areg[k], acc[ty], 0, 0, 0);
        }
      }
    }
    // elementwise: acc[ty][r] = gate ty for (row arow, h-dim hd0+r)
    u16 hvals[4];
#pragma unroll
    for (int r = 0; r < 4; r++) {
      float gi = acc[0][r] + b2f(xv[r])      + biasS[hi * 4 + r];
      float gf = acc[1][r] + b2f(xv[4 + r])  + biasS[16 + hi * 4 + r];
      float gg = acc[2][r] + b2f(xv[8 + r])  + biasS[32 + hi * 4 + r];
      float go = acc[3][r] + b2f(xv[12 + r]) + biasS[48 + hi * 4 + r];
      float c_new = sigm_(gf) * c_reg[r] + sigm_(gi) * tanh_(gg);
      float h_new = sigm_(go) * tanh_(c_new);
      c_reg[r] = c_new;
      hvals[r] = f2b(h_new);
    }
    {
      u32x2 packed;
      packed.x = (u32)hvals[0] | ((u32)hvals[1] << 16);
      packed.y = (u32)hvals[2] | ((u32)hvals[3] << 16);
      store_h64(&hout[((size_t)dir * NB + arow) * KPAD + hd0], packed);
      // drain h stores, block-wide order, then signal
      asm volatile("s_waitcnt vmcnt(0)" ::: "memory");
      __syncthreads();
      if (tid == 0) store_flag(&flagbase[ctile], (unsigned)(s + 1));
      // next-step xg prefetch first, then h_cat (both overlap peers' waits)
      const int sn = (s < 31) ? (s + 1) : 31;
      const int tn = dir ? (31 - sn) : sn;
      const u16* xr = xg + (size_t)(tn * 128 + arow) * XGC + dir * G4 + ar0 + hi * 4;
#pragma unroll
      for (int ty = 0; ty < 4; ty++)
        *(u32x2*)&xv[ty * 4] = *(const u32x2*)&xr[ty * 16];
      *(u32x2*)&h_cat[(size_t)(t * 128 + arow) * 800 + dir * HDIM + hd0] = packed;
    }
    u16* tmp = (u16*)hin; hin = hout; hout = tmp;
  }
}

// ---------- a/bm projection: [4096][200] = h1 @ W1ab^T, written permuted ----------
__global__ __launch_bounds__(256) void ab_gemm(
    const u16* __restrict__ h1, const u16* __restrict__ W1ab,
    const float* __restrict__ smallf, float* __restrict__ abuf, float* __restrict__ bbuf) {
  int lane = threadIdx.x & 63, wv = threadIdx.x >> 6;
  int mt = blockIdx.y * 4 + wv;
  int nt = blockIdx.x;
  int r0 = mt * 16, c0 = nt * 16;
  f32x4 acc = {};
  int fr = lane & 15, fk8 = (lane >> 4) * 8;
  for (int k0 = 0; k0 < 800; k0 += 32) {
    bf16x8 a = *(const bf16x8*)&h1[(size_t)(r0 + fr) * 800 + k0 + fk8];
    bf16x8 b = *(const bf16x8*)&W1ab[(size_t)(c0 + fr) * 800 + k0 + fk8];
    acc = __builtin_amdgcn_mfma_f32_16x16x32_bf16(a, b, acc, 0, 0, 0);
  }
  int c = c0 + fr;
  if (c < 200) {
#pragma unroll
    for (int r = 0; r < 4; r++) {
      int row = r0 + (lane >> 4) * 4 + r;
      int t = row >> 7, n = row & 127;
      int orow = n * 32 + t;
      float v = acc[r];
      if (c < 100) abuf[(size_t)orow * 100 + c] = v;
      else         bbuf[(size_t)orow * 100 + (c - 100)] = v + smallf[c - 100];
    }
  }
}

// ---------- fused pairwise MLP ----------
__global__ __launch_bounds__(256) void pairwise(
    const float* __restrict__ abuf, const float* __restrict__ bbuf,
    const float* __restrict__ smallf, float* __restrict__ outp) {
  __shared__ float aS[16 * 101];
  __shared__ float bS[16 * 101];
  __shared__ float w2S[104];
  int b = blockIdx.z, i0 = blockIdx.y * 16, j0 = blockIdx.x * 16;
  int tid = threadIdx.x;
  for (int idx = tid; idx < 1600; idx += 256) {
    int r = idx / 100, h = idx - r * 100;
    aS[r * 101 + h] = abuf[((size_t)(i0 + r) * 32 + b) * 100 + h];
    bS[r * 101 + h] = bbuf[((size_t)(j0 + r) * 32 + b) * 100 + h];
  }
  if (tid < 100) w2S[tid] = smallf[100 + tid];
  __syncthreads();
  float bias2 = smallf[200];
  int di = tid >> 4, dj = tid & 15;
  const float* ar = &aS[di * 101];
  const float* br = &bS[dj * 101];
  float s = 0.0f;
#pragma unroll 4
  for (int h = 0; h < 100; h++) s += w2S[h] * tanh_(ar[h] + br[h]);
  int i = i0 + di, j = j0 + dj;
  outp[((size_t)(i * 128 + j)) * 32 + b] = s + bias2;
}

// ---------- host ----------
extern "C" void kernel_launch(void* const* d_in, const int* in_sizes, int n_in,
                              void* d_out, int out_size, void* d_ws, size_t ws_size,
                              hipStream_t stream) {
  (void)in_sizes; (void)n_in; (void)out_size; (void)ws_size;
  const int* words = (const int*)d_in[0];
  const int* tags  = (const int*)d_in[1];
  const float* wemb = (const float*)d_in[4];
  const float* temb = (const float*)d_in[5];
  const float* wih[4] = {(const float*)d_in[6],  (const float*)d_in[10],
                         (const float*)d_in[14], (const float*)d_in[18]};
  const float* whh[4] = {(const float*)d_in[7],  (const float*)d_in[11],
                         (const float*)d_in[15], (const float*)d_in[19]};
  const float* bih[4] = {(const float*)d_in[8],  (const float*)d_in[12],
                         (const float*)d_in[16], (const float*)d_in[20]};
  const float* bhh[4] = {(const float*)d_in[9],  (const float*)d_in[13],
                         (const float*)d_in[17], (const float*)d_in[21]};
  const float* w1 = (const float*)d_in[22];
  const float* b1 = (const float*)d_in[23];
  const float* w2 = (const float*)d_in[24];
  const float* b2 = (const float*)d_in[25];
  float* out = (float*)d_out;

  char* ws = (char*)d_ws;
  size_t off = 0;
  auto alloc = [&](size_t bytes) -> void* {
    void* p = ws + off; off = (off + bytes + 255) & ~(size_t)255; return p;
  };
  u16*      hstate= (u16*)     alloc((size_t)2 * 2 * NB * KPAD * 2);  // ping+pong (never memset)
  unsigned* flags = (unsigned*)alloc(1024);                           // 2 layers x 4 groups x 32
  float*    smallf= (float*)   alloc(201 * 4);
  float*    abuf  = (float*)   alloc((size_t)TOK * 100 * 4);
  float*    bbuf  = (float*)   alloc((size_t)TOK * 100 * 4);
  u16*      hcat0 = (u16*)     alloc((size_t)TOK * 800 * 2);
  u16*      hcat1 = (u16*)     alloc((size_t)TOK * 800 * 2);
  u16*      XP    = (u16*)     alloc((size_t)TOK * KPAD * 2);
  u16*      xg    = (u16*)     alloc((size_t)TOK * XGC * 2);          // 26.2 MB
  u16*      W0a   = (u16*)     alloc((size_t)2 * G4 * KPAD * 2);
  u16*      W1a   = (u16*)     alloc((size_t)2 * G4 * 800 * 2);
  u16*      WhhA  = (u16*)     alloc((size_t)4 * G4 * KPAD * 2);
  float*    biasA = (float*)   alloc((size_t)4 * G4 * 4);
  u16*      W1ab  = (u16*)     alloc((size_t)208 * 800 * 2);

  u16* h0 = hstate;
  u16* h1 = hstate + (size_t)2 * NB * KPAD;

  (void)hipMemsetAsync(flags, 0, 1024, stream);              // only required memset
  prep_embed<<<32677, 256, 0, stream>>>(
      wih[0], wih[1], wih[2], wih[3], whh[0], whh[1], whh[2], whh[3],
      bih[0], bih[1], bih[2], bih[3], bhh[0], bhh[1], bhh[2], bhh[3],
      w1, b1, w2, b2, words, tags, wemb, temb,
      W0a, W1a, WhhA, biasA, W1ab, smallf, XP);

  // layer 0: xg = XP @ W0a^T ; persistent recurrence
  gemm_bt<<<dim3(25, 32), 256, 0, stream>>>(XP, W0a, xg, TOK, XGC, KPAD);
  lstm_persist<<<dim3(25, 2, 2), 256, 0, stream>>>(
      xg, WhhA, biasA, h0, h1, hcat0, flags);

  // layer 1: xg = hcat0 @ W1a^T ; persistent recurrence
  gemm_bt<<<dim3(25, 32), 256, 0, stream>>>(hcat0, W1a, xg, TOK, XGC, 800);
  lstm_persist<<<dim3(25, 2, 2), 256, 0, stream>>>(
      xg, WhhA + (size_t)2 * G4 * KPAD, biasA + 2 * G4, h0, h1, hcat1, flags + 128);

  ab_gemm<<<dim3(13, 64), 256, 0, stream>>>(hcat1, W1ab, smallf, abuf, bbuf);
  pairwise<<<dim3(8, 8, 32), 256, 0, stream>>>(abuf, bbuf, smallf, out);
}